// Round 1
// baseline (151.906 us; speedup 1.0000x reference)
//
#include <hip/hip_runtime.h>
#include <math.h>

// GAT: B=32, N=1024, F=64, H=3, D=16
constexpr int Bc = 32, Nn = 1024, Fc = 64, Hc = 3, Dc = 16;
constexpr float ALPHAc = 0.2f;
constexpr float MASKV  = -9.0e15f;
constexpr float L2E    = 1.44269504088896340736f;

constexpr int R = 4;                         // rows per 16-lane group
constexpr int GROUPS = 16;                   // 256 threads / 16 lanes
constexpr int ROWS_PER_BLOCK = R * GROUPS;   // 64
constexpr int TILES = Nn / ROWS_PER_BLOCK;   // 16

// ---------------------------------------------------------------------------
// Kernel 1: Wh[b,h,n,:] = h[b,n,:] @ W[h]  (64x16 per row), then
//           s1 = Wh . a1, s2 = Wh . a2.  One thread per (b,h,n).
// ---------------------------------------------------------------------------
__global__ __launch_bounds__(256) void gat_stage1(
    const float* __restrict__ hbuf, const float* __restrict__ W,
    const float* __restrict__ a, float* __restrict__ Wh,
    float* __restrict__ s1, float* __restrict__ s2)
{
    int idx = blockIdx.x * 256 + threadIdx.x;       // (b*H + h)*N + n
    if (idx >= Bc * Hc * Nn) return;
    int n  = idx & (Nn - 1);
    int bh = idx >> 10;
    int hh = bh % Hc;
    int b  = bh / Hc;

    const float4* hrow = (const float4*)(hbuf + ((size_t)b * Nn + n) * Fc);
    const float*  Wp   = W + (size_t)hh * Fc * Dc;

    float acc[Dc];
#pragma unroll
    for (int d = 0; d < Dc; ++d) acc[d] = 0.f;

#pragma unroll
    for (int q16 = 0; q16 < Fc / 4; ++q16) {
        float4 hv4 = hrow[q16];
#pragma unroll
        for (int c = 0; c < 4; ++c) {
            float hv = (c == 0) ? hv4.x : (c == 1) ? hv4.y : (c == 2) ? hv4.z : hv4.w;
            int f = 4 * q16 + c;
            const float4* wr = (const float4*)(Wp + f * Dc);
#pragma unroll
            for (int q = 0; q < 4; ++q) {
                float4 wv = wr[q];
                acc[4*q+0] = fmaf(hv, wv.x, acc[4*q+0]);
                acc[4*q+1] = fmaf(hv, wv.y, acc[4*q+1]);
                acc[4*q+2] = fmaf(hv, wv.z, acc[4*q+2]);
                acc[4*q+3] = fmaf(hv, wv.w, acc[4*q+3]);
            }
        }
    }

    float4* whp = (float4*)(Wh + (size_t)idx * Dc);
#pragma unroll
    for (int q = 0; q < 4; ++q)
        whp[q] = make_float4(acc[4*q+0], acc[4*q+1], acc[4*q+2], acc[4*q+3]);

    // a: (H, 2D, 1) -> a1 = a[h][0:16], a2 = a[h][16:32]
    const float* ap = a + (size_t)hh * 2 * Dc;
    float t1 = 0.f, t2 = 0.f;
#pragma unroll
    for (int d = 0; d < Dc; ++d) {
        t1 = fmaf(acc[d], ap[d],       t1);
        t2 = fmaf(acc[d], ap[Dc + d],  t2);
    }
    s1[idx] = t1;
    s2[idx] = t2;
}

// ---------------------------------------------------------------------------
// Kernel 2: flash-style softmax aggregation.
//   e[i,j] = lrelu(s1[i]+s2[j]) masked by adj; attn = softmax_j(e);
//   out[b,i,h*16+d] = sum_j attn[i,j] * Wh[b,h,j,d]
// Block: 256 thr = 16 groups x 16 lanes. Group owns R=4 rows i; lanes split j.
// Two passes: (1) exact row max + adj mask bits, (2) exp-weighted accumulate.
// ---------------------------------------------------------------------------
__global__ __launch_bounds__(256, 4) void gat_attn(
    const float* __restrict__ Wh, const float* __restrict__ s1g,
    const float* __restrict__ s2g, const float* __restrict__ adj,
    float* __restrict__ out)
{
    __shared__ float s2s[Nn];

    int bid  = blockIdx.x;
    int tile = bid % TILES;
    int bh   = bid / TILES;
    int hh   = bh % Hc;
    int b    = bh / Hc;
    int t    = threadIdx.x;

    // stage s2 row-block (4 KB)
    ((float4*)s2s)[t] = ((const float4*)(s2g + (size_t)bh * Nn))[t];
    __syncthreads();

    int group = t >> 4;
    int gl    = t & 15;
    int i0    = tile * ROWS_PER_BLOCK + group * R;

    const float* s1p = s1g + (size_t)bh * Nn;
    float s1v[R];
#pragma unroll
    for (int r = 0; r < R; ++r) s1v[r] = s1p[i0 + r];

    const float* Whp = Wh + (size_t)bh * Nn * Dc;

    // ---- pass 1: row max (mask-aware) + adj bitmask (1 bit per k-step) ----
    float m[R];
    unsigned long long mb[R];
#pragma unroll
    for (int r = 0; r < R; ++r) { m[r] = -INFINITY; mb[r] = 0ull; }

    for (int k = 0; k < Nn / 16; ++k) {
        int j = k * 16 + gl;
        float s2j = s2s[j];
        unsigned long long bit = 1ull << k;
#pragma unroll
        for (int r = 0; r < R; ++r) {
            float aij = adj[(size_t)(i0 + r) * Nn + j];
            float x = s1v[r] + s2j;
            float e = fmaxf(x, ALPHAc * x);      // leaky_relu, alpha<1
            bool ok = aij > 0.f;
            mb[r] |= ok ? 0ull : bit;
            e = ok ? e : MASKV;
            m[r] = fmaxf(m[r], e);
        }
    }
#pragma unroll
    for (int r = 0; r < R; ++r) {
#pragma unroll
        for (int off = 1; off < 16; off <<= 1)
            m[r] = fmaxf(m[r], __shfl_xor(m[r], off, 64));
    }

    float nmL2[R], z[R];
    float acc[R][Dc];
#pragma unroll
    for (int r = 0; r < R; ++r) {
        nmL2[r] = -m[r] * L2E;
        z[r] = 0.f;
#pragma unroll
        for (int d = 0; d < Dc; ++d) acc[r][d] = 0.f;
    }

    // ---- pass 2: weighted accumulation (Wh rows streamed from L2) ----
    for (int k = 0; k < Nn / 16; ++k) {
        int j = k * 16 + gl;
        float s2j = s2s[j];
        const float4* wr = (const float4*)(Whp + (size_t)j * Dc);
        float4 w0 = wr[0], w1 = wr[1], w2 = wr[2], w3 = wr[3];
        unsigned long long bit = 1ull << k;
#pragma unroll
        for (int r = 0; r < R; ++r) {
            float x = s1v[r] + s2j;
            float e = fmaxf(x, ALPHAc * x);
            e = (mb[r] & bit) ? MASKV : e;
            // w = exp(e - m) = exp2(e*log2e - m*log2e); masked -> exp2(-1.3e16)=0
            float w = __builtin_amdgcn_exp2f(fmaf(e, L2E, nmL2[r]));
            z[r] += w;
            acc[r][ 0] = fmaf(w, w0.x, acc[r][ 0]);
            acc[r][ 1] = fmaf(w, w0.y, acc[r][ 1]);
            acc[r][ 2] = fmaf(w, w0.z, acc[r][ 2]);
            acc[r][ 3] = fmaf(w, w0.w, acc[r][ 3]);
            acc[r][ 4] = fmaf(w, w1.x, acc[r][ 4]);
            acc[r][ 5] = fmaf(w, w1.y, acc[r][ 5]);
            acc[r][ 6] = fmaf(w, w1.z, acc[r][ 6]);
            acc[r][ 7] = fmaf(w, w1.w, acc[r][ 7]);
            acc[r][ 8] = fmaf(w, w2.x, acc[r][ 8]);
            acc[r][ 9] = fmaf(w, w2.y, acc[r][ 9]);
            acc[r][10] = fmaf(w, w2.z, acc[r][10]);
            acc[r][11] = fmaf(w, w2.w, acc[r][11]);
            acc[r][12] = fmaf(w, w3.x, acc[r][12]);
            acc[r][13] = fmaf(w, w3.y, acc[r][13]);
            acc[r][14] = fmaf(w, w3.z, acc[r][14]);
            acc[r][15] = fmaf(w, w3.w, acc[r][15]);
        }
    }

    // ---- reduce z and acc across the 16 lanes of the group ----
#pragma unroll
    for (int r = 0; r < R; ++r) {
#pragma unroll
        for (int off = 1; off < 16; off <<= 1) {
            z[r] += __shfl_xor(z[r], off, 64);
#pragma unroll
            for (int d = 0; d < Dc; ++d)
                acc[r][d] += __shfl_xor(acc[r][d], off, 64);
        }
    }

    if (gl == 0) {
#pragma unroll
        for (int r = 0; r < R; ++r) {
            float inv = 1.0f / z[r];
            int i = i0 + r;
            float* op = out + ((size_t)b * Nn + i) * (Hc * Dc) + hh * Dc;
            ((float4*)op)[0] = make_float4(acc[r][ 0]*inv, acc[r][ 1]*inv, acc[r][ 2]*inv, acc[r][ 3]*inv);
            ((float4*)op)[1] = make_float4(acc[r][ 4]*inv, acc[r][ 5]*inv, acc[r][ 6]*inv, acc[r][ 7]*inv);
            ((float4*)op)[2] = make_float4(acc[r][ 8]*inv, acc[r][ 9]*inv, acc[r][10]*inv, acc[r][11]*inv);
            ((float4*)op)[3] = make_float4(acc[r][12]*inv, acc[r][13]*inv, acc[r][14]*inv, acc[r][15]*inv);
        }
    }
}

// ---------------------------------------------------------------------------
extern "C" void kernel_launch(void* const* d_in, const int* in_sizes, int n_in,
                              void* d_out, int out_size, void* d_ws, size_t ws_size,
                              hipStream_t stream)
{
    const float* hbuf = (const float*)d_in[0];   // (B,N,F)
    const float* adj  = (const float*)d_in[1];   // (N,N)
    const float* W    = (const float*)d_in[2];   // (H,F,D)
    const float* a    = (const float*)d_in[3];   // (H,2D,1)
    float* out = (float*)d_out;                  // (B,N,H*D) fp32

    // workspace: Wh (B*H*N*D) | s1 (B*H*N) | s2 (B*H*N)  = ~7.1 MB
    float* Wh = (float*)d_ws;
    float* s1 = Wh + (size_t)Bc * Hc * Nn * Dc;
    float* s2 = s1 + (size_t)Bc * Hc * Nn;

    gat_stage1<<<dim3((Bc * Hc * Nn) / 256), dim3(256), 0, stream>>>(
        hbuf, W, a, Wh, s1, s2);
    gat_attn<<<dim3(Bc * Hc * TILES), dim3(256), 0, stream>>>(
        Wh, s1, s2, adj, out);
}

// Round 2
// 78.940 us; speedup vs baseline: 1.9243x; 1.9243x over previous
//
#include <hip/hip_runtime.h>
#include <math.h>

// GAT: B=32, N=1024, F=64, H=3, D=16
constexpr int Bc = 32, Nn = 1024, Fc = 64, Hc = 3, Dc = 16;
constexpr float ALPHAc = 0.2f;
constexpr float MASKV  = -9.0e15f;
constexpr float L2E    = 1.44269504088896340736f;

typedef __bf16 bf16x8 __attribute__((ext_vector_type(8)));
typedef float  f32x4  __attribute__((ext_vector_type(4)));

// ---------------------------------------------------------------------------
// Kernel 0: pack adj>0 into a bitmask. bit (j&7) of byte [i*128 + j/8].
// 131072 bytes total; one byte per thread.
// ---------------------------------------------------------------------------
__global__ __launch_bounds__(256) void gat_pack(
    const float* __restrict__ adj, unsigned char* __restrict__ bits)
{
    int idx = blockIdx.x * 256 + threadIdx.x;        // 0 .. 131071
    const float4* p = (const float4*)(adj + (size_t)idx * 8);
    float4 x = p[0], y = p[1];
    unsigned b = 0;
    b |= (x.x > 0.f) ? 1u   : 0u;
    b |= (x.y > 0.f) ? 2u   : 0u;
    b |= (x.z > 0.f) ? 4u   : 0u;
    b |= (x.w > 0.f) ? 8u   : 0u;
    b |= (y.x > 0.f) ? 16u  : 0u;
    b |= (y.y > 0.f) ? 32u  : 0u;
    b |= (y.z > 0.f) ? 64u  : 0u;
    b |= (y.w > 0.f) ? 128u : 0u;
    bits[idx] = (unsigned char)b;
}

// ---------------------------------------------------------------------------
// Kernel 1: Wh = h @ W per (b,h,n); store WhT as bf16 [bh][d][n] (MFMA A
// operand layout, n contiguous) plus s1/s2 score halves (fp32).
// ---------------------------------------------------------------------------
__global__ __launch_bounds__(256) void gat_stage1(
    const float* __restrict__ hbuf, const float* __restrict__ W,
    const float* __restrict__ a, __bf16* __restrict__ WhT,
    float* __restrict__ s1, float* __restrict__ s2)
{
    int idx = blockIdx.x * 256 + threadIdx.x;       // (b*H + h)*N + n
    if (idx >= Bc * Hc * Nn) return;
    int n  = idx & (Nn - 1);
    int bh = idx >> 10;
    int hh = bh % Hc;
    int b  = bh / Hc;

    const float4* hrow = (const float4*)(hbuf + ((size_t)b * Nn + n) * Fc);
    const float*  Wp   = W + (size_t)hh * Fc * Dc;

    float acc[Dc];
#pragma unroll
    for (int d = 0; d < Dc; ++d) acc[d] = 0.f;

#pragma unroll
    for (int q16 = 0; q16 < Fc / 4; ++q16) {
        float4 hv4 = hrow[q16];
#pragma unroll
        for (int c = 0; c < 4; ++c) {
            float hv = (c == 0) ? hv4.x : (c == 1) ? hv4.y : (c == 2) ? hv4.z : hv4.w;
            int f = 4 * q16 + c;
            const float4* wr = (const float4*)(Wp + f * Dc);
#pragma unroll
            for (int q = 0; q < 4; ++q) {
                float4 wv = wr[q];
                acc[4*q+0] = fmaf(hv, wv.x, acc[4*q+0]);
                acc[4*q+1] = fmaf(hv, wv.y, acc[4*q+1]);
                acc[4*q+2] = fmaf(hv, wv.z, acc[4*q+2]);
                acc[4*q+3] = fmaf(hv, wv.w, acc[4*q+3]);
            }
        }
    }

    // WhT[bh][d][n] bf16 — 16 coalesced 2B stores (lanes are consecutive n)
#pragma unroll
    for (int d = 0; d < Dc; ++d)
        WhT[((size_t)bh * Dc + d) * Nn + n] = (__bf16)acc[d];

    const float* ap = a + (size_t)hh * 2 * Dc;
    float t1 = 0.f, t2 = 0.f;
#pragma unroll
    for (int d = 0; d < Dc; ++d) {
        t1 = fmaf(acc[d], ap[d],      t1);
        t2 = fmaf(acc[d], ap[Dc + d], t2);
    }
    s1[idx] = t1;
    s2[idx] = t2;
}

// ---------------------------------------------------------------------------
// Kernel 1b: per-(b,h) softmax shift  m_ub = lrelu(max_i s1 + max_j s2);
// store nm = -m_ub * log2(e).  One block per bh.
// ---------------------------------------------------------------------------
__global__ __launch_bounds__(256) void gat_maxes(
    const float* __restrict__ s1, const float* __restrict__ s2,
    float* __restrict__ nmg)
{
    __shared__ float r1[4], r2[4];
    int bh = blockIdx.x, t = threadIdx.x;
    const float* p1 = s1 + (size_t)bh * Nn;
    const float* p2 = s2 + (size_t)bh * Nn;
    float m1 = -INFINITY, m2 = -INFINITY;
#pragma unroll
    for (int k = 0; k < 4; ++k) {
        m1 = fmaxf(m1, p1[t + 256 * k]);
        m2 = fmaxf(m2, p2[t + 256 * k]);
    }
#pragma unroll
    for (int off = 1; off < 64; off <<= 1) {
        m1 = fmaxf(m1, __shfl_xor(m1, off, 64));
        m2 = fmaxf(m2, __shfl_xor(m2, off, 64));
    }
    if ((t & 63) == 0) { r1[t >> 6] = m1; r2[t >> 6] = m2; }
    __syncthreads();
    if (t == 0) {
        float M1 = fmaxf(fmaxf(r1[0], r1[1]), fmaxf(r1[2], r1[3]));
        float M2 = fmaxf(fmaxf(r2[0], r2[1]), fmaxf(r2[2], r2[3]));
        float x  = M1 + M2;
        float m  = fmaxf(x, ALPHAc * x);        // lrelu(upper bound)
        nmg[bh] = -m * L2E;
    }
}

// ---------------------------------------------------------------------------
// Kernel 2: flash aggregation via MFMA.
//   Per wave: one 16-row i-tile. out^T = WhT(bf16) @ P^T(bf16) with
//   mfma_f32_16x16x32_bf16; P computed in-register from s1+s2+adj bits,
//   shifted by the per-bh bound (no per-row max pass needed).
// Block = 256 thr = 4 waves = 64 rows. Grid = B*H*16.
// ---------------------------------------------------------------------------
__global__ __launch_bounds__(256) void gat_attn_mfma(
    const __bf16* __restrict__ WhT, const float* __restrict__ s1g,
    const float* __restrict__ s2g, const unsigned char* __restrict__ adjbits,
    const float* __restrict__ nmg, float* __restrict__ out)
{
    __shared__ float s2s[Nn];

    int bid  = blockIdx.x;
    int tile = bid & 15;
    int bh   = bid >> 4;
    int hh   = bh % Hc;
    int b    = bh / Hc;
    int t    = threadIdx.x;

    // stage s2 (4 KB), prescaled by log2(e)
    {
        float4 v = ((const float4*)(s2g + (size_t)bh * Nn))[t];
        ((float4*)s2s)[t] = make_float4(v.x * L2E, v.y * L2E, v.z * L2E, v.w * L2E);
    }
    __syncthreads();

    int wave = t >> 6;
    int l    = t & 63;
    int lr   = l & 15;          // A row (=d) / B col (=i) / D col (=i)
    int lg   = l >> 4;          // k-group: k = lg*8 + e

    int i = tile * 64 + wave * 16 + lr;
    float s1L = s1g[(size_t)bh * Nn + i] * L2E;
    float nm  = nmg[bh];                       // -m_ub * log2e
    float s1n = s1L + nm;                      // folded

    const __bf16* Ap  = WhT + ((size_t)bh * Dc + lr) * Nn + lg * 8;
    const unsigned* abp = (const unsigned*)(adjbits + (size_t)i * (Nn / 8));

    f32x4 acc = {0.f, 0.f, 0.f, 0.f};
    float z = 0.f;

    for (int j0 = 0; j0 < Nn; j0 += 32) {
        const float4* s2p = (const float4*)&s2s[j0 + lg * 8];
        float4 sa = s2p[0], sb = s2p[1];
        unsigned w  = abp[j0 >> 5];            // 32 adj bits for this j-step
        unsigned m8 = (w >> (lg * 8)) & 0xffu; // this lane's 8 bits

        float s2arr[8] = {sa.x, sa.y, sa.z, sa.w, sb.x, sb.y, sb.z, sb.w};
        bf16x8 pfrag;
        float zp = 0.f;
#pragma unroll
        for (int e = 0; e < 8; ++e) {
            float xL   = s1n + s2arr[e];                   // (s1+s2)*L2E + nm
            float arg  = fmaxf(xL, fmaf(ALPHAc, xL, nm * (1.f - ALPHAc)));
            // lrelu in log2 domain: max((x)*L2E, 0.2*(x)*L2E) + nm
            //   xL already has +nm; second arm: 0.2*(xL-nm)+nm = 0.2*xL+0.8*nm
            arg = (m8 & (1u << e)) ? arg : -INFINITY;
            float pw = __builtin_amdgcn_exp2f(arg);
            zp += pw;
            pfrag[e] = (__bf16)pw;
        }
        z += zp;
        bf16x8 afrag = *(const bf16x8*)(Ap + j0);
        acc = __builtin_amdgcn_mfma_f32_16x16x32_bf16(afrag, pfrag, acc, 0, 0, 0);
    }

    // z partial covers k-slice lg; sum across the 4 lanes sharing lr
    z += __shfl_xor(z, 16, 64);
    z += __shfl_xor(z, 32, 64);
    float inv = 1.f / z;

    // D[row=d=lg*4+reg][col=i=lr]  ->  out[b][i][hh*16 + d]
    float* op = out + ((size_t)b * Nn + i) * (Hc * Dc) + hh * Dc + lg * 4;
    *(float4*)op = make_float4(acc[0] * inv, acc[1] * inv, acc[2] * inv, acc[3] * inv);
}

// ---------------------------------------------------------------------------
extern "C" void kernel_launch(void* const* d_in, const int* in_sizes, int n_in,
                              void* d_out, int out_size, void* d_ws, size_t ws_size,
                              hipStream_t stream)
{
    const float* hbuf = (const float*)d_in[0];   // (B,N,F)
    const float* adj  = (const float*)d_in[1];   // (N,N)
    const float* W    = (const float*)d_in[2];   // (H,F,D)
    const float* a    = (const float*)d_in[3];   // (H,2D,1)
    float* out = (float*)d_out;                  // (B,N,H*D) fp32

    // workspace: WhT bf16 (96*16*1024) | s1 | s2 | nm | adjbits  ~ 4.1 MB
    __bf16* WhT = (__bf16*)d_ws;
    float* s1   = (float*)(WhT + (size_t)Bc * Hc * Dc * Nn);
    float* s2   = s1 + (size_t)Bc * Hc * Nn;
    float* nmg  = s2 + (size_t)Bc * Hc * Nn;
    unsigned char* adjbits = (unsigned char*)(nmg + Bc * Hc);

    gat_pack<<<dim3(Nn * Nn / 8 / 256), dim3(256), 0, stream>>>(adj, adjbits);
    gat_stage1<<<dim3((Bc * Hc * Nn) / 256), dim3(256), 0, stream>>>(
        hbuf, W, a, WhT, s1, s2);
    gat_maxes<<<dim3(Bc * Hc), dim3(256), 0, stream>>>(s1, s2, nmg);
    gat_attn_mfma<<<dim3(Bc * Hc * 16), dim3(256), 0, stream>>>(
        WhT, s1, s2, adjbits, nmg, out);
}

// Round 3
// 63.532 us; speedup vs baseline: 2.3910x; 1.2425x over previous
//
#include <hip/hip_runtime.h>
#include <math.h>

// GAT: B=32, N=1024, F=64, H=3, D=16
constexpr int Bc = 32, Nn = 1024, Fc = 64, Hc = 3, Dc = 16;
constexpr float ALPHAc = 0.2f;
constexpr float L2E    = 1.44269504088896340736f;

typedef __bf16 bf16x8 __attribute__((ext_vector_type(8)));
typedef float  f32x4  __attribute__((ext_vector_type(4)));

__device__ __forceinline__ unsigned enc_f32(float x) {
    unsigned b = __builtin_bit_cast(unsigned, x);
    return (b & 0x80000000u) ? ~b : (b | 0x80000000u);
}
__device__ __forceinline__ float dec_f32(unsigned e) {
    unsigned b = (e & 0x80000000u) ? (e ^ 0x80000000u) : ~e;
    return __builtin_bit_cast(float, b);
}

// ---------------------------------------------------------------------------
// Kernel 0: pack adj>0 bitmask (bit j&7 of byte i*128+j/8); also init c2enc.
// ---------------------------------------------------------------------------
__global__ __launch_bounds__(256) void gat_pack(
    const float* __restrict__ adj, unsigned char* __restrict__ bits,
    unsigned* __restrict__ c2enc)
{
    int idx = blockIdx.x * 256 + threadIdx.x;        // 0 .. 131071
    if (blockIdx.x == 0 && threadIdx.x < Bc * Hc) c2enc[threadIdx.x] = 0u;
    const float4* p = (const float4*)(adj + (size_t)idx * 8);
    float4 x = p[0], y = p[1];
    unsigned b = 0;
    b |= (x.x > 0.f) ? 1u   : 0u;
    b |= (x.y > 0.f) ? 2u   : 0u;
    b |= (x.z > 0.f) ? 4u   : 0u;
    b |= (x.w > 0.f) ? 8u   : 0u;
    b |= (y.x > 0.f) ? 16u  : 0u;
    b |= (y.y > 0.f) ? 32u  : 0u;
    b |= (y.z > 0.f) ? 64u  : 0u;
    b |= (y.w > 0.f) ? 128u : 0u;
    bits[idx] = (unsigned char)b;
}

// ---------------------------------------------------------------------------
// Kernel 1: Wh = h @ W per (b,h,n); WhT bf16 [bh][d][n]; s1/s2 fp32; and
// per-bh max_j(s2) via encoded atomicMax (for the softmax shift).
// ---------------------------------------------------------------------------
__global__ __launch_bounds__(256) void gat_stage1(
    const float* __restrict__ hbuf, const float* __restrict__ W,
    const float* __restrict__ a, __bf16* __restrict__ WhT,
    float* __restrict__ s1, float* __restrict__ s2,
    unsigned* __restrict__ c2enc)
{
    int idx = blockIdx.x * 256 + threadIdx.x;       // (b*H + h)*N + n
    int n  = idx & (Nn - 1);
    int bh = idx >> 10;
    int hh = bh % Hc;
    int b  = bh / Hc;

    const float4* hrow = (const float4*)(hbuf + ((size_t)b * Nn + n) * Fc);
    const float*  Wp   = W + (size_t)hh * Fc * Dc;

    float acc[Dc];
#pragma unroll
    for (int d = 0; d < Dc; ++d) acc[d] = 0.f;

#pragma unroll
    for (int q16 = 0; q16 < Fc / 4; ++q16) {
        float4 hv4 = hrow[q16];
#pragma unroll
        for (int c = 0; c < 4; ++c) {
            float hv = (c == 0) ? hv4.x : (c == 1) ? hv4.y : (c == 2) ? hv4.z : hv4.w;
            int f = 4 * q16 + c;
            const float4* wr = (const float4*)(Wp + f * Dc);
#pragma unroll
            for (int q = 0; q < 4; ++q) {
                float4 wv = wr[q];
                acc[4*q+0] = fmaf(hv, wv.x, acc[4*q+0]);
                acc[4*q+1] = fmaf(hv, wv.y, acc[4*q+1]);
                acc[4*q+2] = fmaf(hv, wv.z, acc[4*q+2]);
                acc[4*q+3] = fmaf(hv, wv.w, acc[4*q+3]);
            }
        }
    }

#pragma unroll
    for (int d = 0; d < Dc; ++d)
        WhT[((size_t)bh * Dc + d) * Nn + n] = (__bf16)acc[d];

    const float* ap = a + (size_t)hh * 2 * Dc;
    float t1 = 0.f, t2 = 0.f;
#pragma unroll
    for (int d = 0; d < Dc; ++d) {
        t1 = fmaf(acc[d], ap[d],      t1);
        t2 = fmaf(acc[d], ap[Dc + d], t2);
    }
    s1[idx] = t1;
    s2[idx] = t2;

    // per-bh max of s2 (wave covers one bh only: blocks are 256 n's of one bh)
    float m2 = t2;
#pragma unroll
    for (int off = 1; off < 64; off <<= 1)
        m2 = fmaxf(m2, __shfl_xor(m2, off, 64));
    if ((threadIdx.x & 63) == 0)
        atomicMax(&c2enc[bh], enc_f32(m2));
}

// ---------------------------------------------------------------------------
// Kernel 2: flash aggregation via MFMA, exp2-free inner loop.
//   w'_ij = (s1+s2>0) ? B_j : R_i*D_j   (softmax row-scale invariance)
//   B_j = 2^(s2L+c2), D_j = 2^(0.2 s2L+c2), R_i = 2^(-0.8 s1L),
//   sel via B_j > Tb_i = 2^(c2-s1L). z from second MFMA (A=ones).
// Block = 256 = 4 waves; wave owns 16 rows. Grid = B*H*16.
// ---------------------------------------------------------------------------
__global__ __launch_bounds__(256) void gat_attn_mfma(
    const __bf16* __restrict__ WhT, const float* __restrict__ s1g,
    const float* __restrict__ s2g, const unsigned char* __restrict__ adjbits,
    const unsigned* __restrict__ c2enc, float* __restrict__ out)
{
    __shared__ unsigned s2pk[Nn];   // [D_bf16 | B_bf16] per j (4 KB)

    int bid  = blockIdx.x;
    int tile = bid & 15;
    int bh   = bid >> 4;
    int hh   = bh % Hc;
    int b    = bh / Hc;
    int t    = threadIdx.x;

    float c2 = -dec_f32(c2enc[bh]) * L2E;

    // stage packed B/D (each thread does 4 j's; 8 exp2 total)
    {
        float4 v = ((const float4*)(s2g + (size_t)bh * Nn))[t];
        unsigned pk[4];
        float sv[4] = {v.x, v.y, v.z, v.w};
#pragma unroll
        for (int q = 0; q < 4; ++q) {
            float Bf = __builtin_amdgcn_exp2f(fmaf(sv[q], L2E, c2));
            float Df = __builtin_amdgcn_exp2f(fmaf(sv[q], ALPHAc * L2E, c2));
            unsigned bb = (unsigned)__builtin_bit_cast(unsigned short, (__bf16)Bf);
            unsigned db = (unsigned)__builtin_bit_cast(unsigned short, (__bf16)Df);
            pk[q] = (db << 16) | bb;
        }
        ((uint4*)s2pk)[t] = make_uint4(pk[0], pk[1], pk[2], pk[3]);
    }
    __syncthreads();

    int wave = t >> 6;
    int l    = t & 63;
    int lr   = l & 15;          // A row (=d) / D col (=i)
    int lg   = l >> 4;          // k-group: k = lg*8 + e

    int i = tile * 64 + wave * 16 + lr;
    float s1v = s1g[(size_t)bh * Nn + i];
    float Tb  = __builtin_amdgcn_exp2f(fmaf(-s1v, L2E, c2));
    float R   = __builtin_amdgcn_exp2f(s1v * (-0.8f * L2E));

    const __bf16*  Ap   = WhT + ((size_t)bh * Dc + lr) * Nn + lg * 8;
    const uint4*   abp4 = (const uint4*)(adjbits + (size_t)i * (Nn / 8));

    bf16x8 ones;
#pragma unroll
    for (int e = 0; e < 8; ++e) ones[e] = (__bf16)1.0f;

    f32x4 acc  = {0.f, 0.f, 0.f, 0.f};
    f32x4 accz = {0.f, 0.f, 0.f, 0.f};

    uint4 mnext = abp4[0];
    for (int o = 0; o < 8; ++o) {
        uint4 mrow = mnext;
        if (o < 7) mnext = abp4[o + 1];
#pragma unroll
        for (int q = 0; q < 4; ++q) {
            unsigned w32 = (q == 0) ? mrow.x : (q == 1) ? mrow.y
                         : (q == 2) ? mrow.z : mrow.w;
            int j0 = o * 128 + q * 32;
            unsigned m8 = (w32 >> (lg * 8)) & 0xffu;

            const uint4* sp = (const uint4*)&s2pk[j0 + lg * 8];
            uint4 pa = sp[0], pb = sp[1];
            unsigned pk8[8] = {pa.x, pa.y, pa.z, pa.w, pb.x, pb.y, pb.z, pb.w};

            bf16x8 pfrag;
#pragma unroll
            for (int e = 0; e < 8; ++e) {
                unsigned u = pk8[e];
                float Bf = __builtin_bit_cast(float, u << 16);
                float Df = __builtin_bit_cast(float, u & 0xffff0000u);
                float w  = (Bf > Tb) ? Bf : (R * Df);
                pfrag[e] = (__bf16)w;
            }
            if (!__all((int)(m8 == 0xffu))) {
#pragma unroll
                for (int e = 0; e < 8; ++e)
                    if (!(m8 & (1u << e))) pfrag[e] = (__bf16)0.f;
            }

            bf16x8 afrag = *(const bf16x8*)(Ap + j0);
            acc  = __builtin_amdgcn_mfma_f32_16x16x32_bf16(afrag, pfrag, acc,  0, 0, 0);
            accz = __builtin_amdgcn_mfma_f32_16x16x32_bf16(ones,  pfrag, accz, 0, 0, 0);
        }
    }

    float inv = 1.0f / accz[0];
    float* op = out + ((size_t)b * Nn + i) * (Hc * Dc) + hh * Dc + lg * 4;
    *(float4*)op = make_float4(acc[0] * inv, acc[1] * inv, acc[2] * inv, acc[3] * inv);
}

// ---------------------------------------------------------------------------
extern "C" void kernel_launch(void* const* d_in, const int* in_sizes, int n_in,
                              void* d_out, int out_size, void* d_ws, size_t ws_size,
                              hipStream_t stream)
{
    const float* hbuf = (const float*)d_in[0];   // (B,N,F)
    const float* adj  = (const float*)d_in[1];   // (N,N)
    const float* W    = (const float*)d_in[2];   // (H,F,D)
    const float* a    = (const float*)d_in[3];   // (H,2D,1)
    float* out = (float*)d_out;                  // (B,N,H*D) fp32

    // ws: WhT bf16 | s1 | s2 | c2enc | adjbits  (~4.1 MB)
    __bf16* WhT = (__bf16*)d_ws;
    float* s1   = (float*)(WhT + (size_t)Bc * Hc * Dc * Nn);
    float* s2   = s1 + (size_t)Bc * Hc * Nn;
    unsigned* c2enc = (unsigned*)(s2 + (size_t)Bc * Hc * Nn);
    unsigned char* adjbits = (unsigned char*)(c2enc + 128);

    gat_pack<<<dim3(Nn * Nn / 8 / 256), dim3(256), 0, stream>>>(adj, adjbits, c2enc);
    gat_stage1<<<dim3((Bc * Hc * Nn) / 256), dim3(256), 0, stream>>>(
        hbuf, W, a, WhT, s1, s2, c2enc);
    gat_attn_mfma<<<dim3(Bc * Hc * 16), dim3(256), 0, stream>>>(
        WhT, s1, s2, adjbits, c2enc, out);
}